// Round 16
// baseline (7309.373 us; speedup 1.0000x reference)
//
#include <hip/hip_runtime.h>
#include <math.h>

// Model: 10 parallel LSTMs -> MI-LSTM w/ stream attention -> linear head.
// All f32 (no fp32-input MFMA on CDNA4; accuracy threshold requires f32).
//
#define SS 10
#define TT 256
#define BB 128
#define HH 128
#define II 128
#define G4 512     // 4H
#define ZK 256     // I + H (fused [x|h] contraction)
#define NCOL 2944  // phase-D fused weight columns: Ui(1280)|Uc(1280)|Uf(128)|Uo(128)|Wa(128)
#define NBLK 184   // cooperative blocks: 8 row-groups x 23 col-groups (16 rows x 128 cols each)

#define SZ_W2T   (SS*ZK*G4)        // 1,310,720
#define SZ_BIAS2 (SS*G4)           // 5,120
#define SZ_UBIG  (HH*NCOL)         // 376,832
#define SZ_TILDE (SS*TT*BB*HH)     // 41,943,040
#define SZ_X     (TT*SS*BB*HH)     // 41,943,040
#define SZ_XFO   (TT*BB*HH)        // 4,194,304

#define OFF_W2T   0
#define OFF_BIAS2 (OFF_W2T + SZ_W2T)
#define OFF_UBIG  (OFF_BIAS2 + SZ_BIAS2)
#define OFF_TILDE (OFF_UBIG + SZ_UBIG)
#define OFF_XI    (OFF_TILDE + SZ_TILDE)
#define OFF_XC    (OFF_XI + SZ_X)
#define OFF_XF    (OFF_XC + SZ_X)
#define OFF_XO    (OFF_XF + SZ_XFO)
#define OFF_HT    (OFF_XO + SZ_XFO)
#define OFF_CT    (OFF_HT + BB*HH)
#define OFF_ACT   (OFF_CT + BB*HH)
#define OFF_CNT   (OFF_ACT + BB*NCOL)

__device__ __forceinline__ float sigf(float x){ return 1.0f/(1.0f+expf(-x)); }

// per-access coherent ops (sc0/sc1 path; no cache-wide wb/inv)
__device__ __forceinline__ float ald(const float* p){
  return __hip_atomic_load(p, __ATOMIC_RELAXED, __HIP_MEMORY_SCOPE_AGENT);
}
__device__ __forceinline__ void ast(float* p, float v){
  __hip_atomic_store(p, v, __ATOMIC_RELAXED, __HIP_MEMORY_SCOPE_AGENT);
}
__device__ __forceinline__ int aldi(const int* p){
  return __hip_atomic_load(p, __ATOMIC_RELAXED, __HIP_MEMORY_SCOPE_AGENT);
}
__device__ __forceinline__ void asti(int* p, int v){
  __hip_atomic_store(p, v, __ATOMIC_RELAXED, __HIP_MEMORY_SCOPE_AGENT);
}
// 16B coherent ops. ext_vector_type binds to a VGPR quad (HIP float4 is a struct, cannot).
typedef float f32x4v __attribute__((ext_vector_type(4)));
__device__ __forceinline__ void ast4(float* p, float a, float b, float c, float d){
  f32x4v w; w.x = a; w.y = b; w.z = c; w.w = d;
  asm volatile("global_store_dwordx4 %0, %1, off sc0 sc1" :: "v"(p), "v"(w) : "memory");
}
__device__ __forceinline__ f32x4v ald4(const float* p){
  f32x4v r;
  asm volatile("global_load_dwordx4 %0, %1, off sc0 sc1" : "=v"(r) : "v"(p) : "memory");
  return r;
}

// ---------------- prep: fused transposed LSTM weights (b128-friendly) ----------------
__global__ __launch_bounds__(256) void prep_w2t(const float* __restrict__ Wih, const float* __restrict__ Whh,
                                                const float* __restrict__ bih, const float* __restrict__ bhh,
                                                float* __restrict__ w2t, float* __restrict__ bias2){
  int idx = blockIdx.x*256 + threadIdx.x;
  if (idx < SZ_W2T){
    int q = idx & 3; int j = (idx >> 2) & 511; int kk4 = (idx >> 11) & 63; int s = idx >> 17;
    int kk = kk4*4 + q;
    float v = (kk < II) ? Wih[(s*G4 + j)*II + kk] : Whh[(s*G4 + j)*HH + (kk - II)];
    w2t[idx] = v;
  }
  if (idx < SZ_BIAS2) bias2[idx] = bih[idx] + bhh[idx];
}

__global__ __launch_bounds__(256) void prep_ubig(const float* __restrict__ Ui, const float* __restrict__ Uc,
                                                 const float* __restrict__ Uf, const float* __restrict__ Uo,
                                                 const float* __restrict__ Wa, float* __restrict__ ubig){
  int idx = blockIdx.x*256 + threadIdx.x;
  if (idx >= SZ_UBIG) return;
  int col = idx % NCOL; int h = idx / NCOL;
  float v;
  if (col < 1280){ int k = col >> 7, d = col & 127; v = Ui[(k*HH + h)*HH + d]; }
  else if (col < 2560){ int c2 = col - 1280; int k = c2 >> 7, d = c2 & 127; v = Uc[(k*HH + h)*HH + d]; }
  else if (col < 2688){ v = Uf[h*HH + (col - 2560)]; }
  else if (col < 2816){ v = Uo[h*HH + (col - 2688)]; }
  else               { v = Wa[h*HH + (col - 2816)]; }
  ubig[idx] = v;
}

// init: flags + h/c state
__global__ __launch_bounds__(256) void init_state(int* flags, float* hR, float* cR){
  int idx = blockIdx.x*256 + threadIdx.x;
  if (idx < 384) flags[idx] = 0;
  if (idx < BB*HH){ hR[idx] = 0.f; cR[idx] = 0.f; }
}

// ---------------- phase B: fused 10x LSTM scan, 4-way split-K, 4r x 4c tiles ----------------
// Thread (q = tid>>8, rh = (tid>>7)&1, j4 = tid&127): rows rh*4..+3, cols j4*4..+3,
// contraction [q*64, q*64+64). z-reads 64/wave/step (was 128); glp writes 4 b128.
__global__ __launch_bounds__(1024) void lstm_scan(const float* __restrict__ feat, const float* __restrict__ w2t,
                                                  const float* __restrict__ bias2, float* __restrict__ tilde){
  int p = blockIdx.x;                 // 0..159
  int g = (p & 7) * 20 + (p >> 3);
  int s = g >> 4; int rb = g & 15; int b0 = rb * 8;
  const int tid = threadIdx.x;
  const int q = tid >> 8;             // 0..3 K-quarter
  const int rh = (tid >> 7) & 1;      // row half
  const int j4 = tid & 127;           // col quad
  __shared__ __align__(16) float z[8][ZK];       // 8KB
  __shared__ __align__(16) float glp[4][8][G4];  // 64KB raw partials
  const float* w2ts = w2t + (size_t)s*ZK*G4;
  const float* wb = w2ts + ((size_t)(q*16)*G4 + j4*4)*4;
  const int r8 = tid >> 7;            // 0..7 (update row)
  const int k8 = tid & 127;
  float b_i = bias2[s*G4 + k8];
  float b_f = bias2[s*G4 + 128 + k8];
  float b_g = bias2[s*G4 + 256 + k8];
  float b_o = bias2[s*G4 + 384 + k8];
  float c = 0.f;
  z[r8][128 + k8] = 0.f;
  z[r8][k8] = feat[((s*TT + 0)*BB + (b0 + r8))*II + k8];
  __syncthreads();
  for (int t = 0; t < TT; ++t){
    float acc[4][4];
    #pragma unroll
    for (int r=0;r<4;++r)
      #pragma unroll
      for (int cc=0;cc<4;++cc) acc[r][cc] = 0.f;
    const float* wp = wb;
    const int kb0 = q*64;
    #pragma unroll 4
    for (int it = 0; it < 16; ++it){
      float4 wv0 = *(const float4*)(wp);
      float4 wv1 = *(const float4*)(wp + 4);
      float4 wv2 = *(const float4*)(wp + 8);
      float4 wv3 = *(const float4*)(wp + 12);
      wp += 4*G4;
      #pragma unroll
      for (int r=0;r<4;++r){
        float4 zv = *(const float4*)&z[rh*4 + r][kb0 + it*4];
        acc[r][0] = fmaf(zv.w, wv0.w, fmaf(zv.z, wv0.z, fmaf(zv.y, wv0.y, fmaf(zv.x, wv0.x, acc[r][0]))));
        acc[r][1] = fmaf(zv.w, wv1.w, fmaf(zv.z, wv1.z, fmaf(zv.y, wv1.y, fmaf(zv.x, wv1.x, acc[r][1]))));
        acc[r][2] = fmaf(zv.w, wv2.w, fmaf(zv.z, wv2.z, fmaf(zv.y, wv2.y, fmaf(zv.x, wv2.x, acc[r][2]))));
        acc[r][3] = fmaf(zv.w, wv3.w, fmaf(zv.z, wv3.z, fmaf(zv.y, wv3.y, fmaf(zv.x, wv3.x, acc[r][3]))));
      }
    }
    #pragma unroll
    for (int r=0;r<4;++r)
      *(float4*)&glp[q][rh*4 + r][j4*4] = make_float4(acc[r][0], acc[r][1], acc[r][2], acc[r][3]);
    __syncthreads();
    {
      float gi = glp[0][r8][k8]       + glp[1][r8][k8]       + glp[2][r8][k8]       + glp[3][r8][k8]       + b_i;
      float gf = glp[0][r8][128 + k8] + glp[1][r8][128 + k8] + glp[2][r8][128 + k8] + glp[3][r8][128 + k8] + b_f;
      float gg = glp[0][r8][256 + k8] + glp[1][r8][256 + k8] + glp[2][r8][256 + k8] + glp[3][r8][256 + k8] + b_g;
      float go = glp[0][r8][384 + k8] + glp[1][r8][384 + k8] + glp[2][r8][384 + k8] + glp[3][r8][384 + k8] + b_o;
      float i_ = sigf(gi), f_ = sigf(gf), g_ = tanhf(gg), o_ = sigf(go);
      c = f_*c + i_*g_;
      float h = o_*tanhf(c);
      z[r8][128 + k8] = h;
      tilde[((s*TT + t)*BB + (b0 + r8))*HH + k8] = fmaxf(h, 0.f);
      if (t+1 < TT)
        z[r8][k8] = feat[((s*TT + (t+1))*BB + (b0 + r8))*II + k8];
    }
    __syncthreads();
  }
}

// ---------------- phase C: projections (unchanged) ----------------
__global__ __launch_bounds__(256) void proj_ic(const float* __restrict__ tilde,
                                               const float* __restrict__ Wi, const float* __restrict__ bi,
                                               const float* __restrict__ Wc, const float* __restrict__ bc,
                                               float* __restrict__ xi, float* __restrict__ xc){
  const int k = blockIdx.y;
  const int isc = blockIdx.z;
  const float* W = (isc ? Wc : Wi) + k*HH*HH;
  const float* bias = (isc ? bc : bi) + k*HH;
  float* out = isc ? xc : xi;
  const int m0 = blockIdx.x * 128;
  const int tid = threadIdx.x;
  __shared__ float Wl[HH*HH];
  __shared__ float Al[32*HH];
  for (int u = 0; u < 64; ++u) Wl[u*256 + tid] = W[u*256 + tid];
  const int tx = tid & 31, ty = tid >> 5;
  const int d0 = tx*4;
  float4 bv = *(const float4*)&bias[d0];
  __syncthreads();
  for (int ch = 0; ch < 4; ++ch){
    const float* Arow = tilde + (size_t)(k*TT*BB + m0 + ch*32)*HH;
    #pragma unroll
    for (int u = 0; u < 4; ++u)
      *(float4*)&Al[u*1024 + tid*4] = *(const float4*)&Arow[u*1024 + tid*4];
    __syncthreads();
    float4 a0 = bv, a1 = bv, a2 = bv, a3 = bv;
    for (int h = 0; h < HH; ++h){
      float4 w4 = *(const float4*)&Wl[h*HH + d0];
      float A0 = Al[(ty   )*HH + h], A1 = Al[(ty+ 8)*HH + h];
      float A2 = Al[(ty+16)*HH + h], A3 = Al[(ty+24)*HH + h];
      a0.x = fmaf(A0,w4.x,a0.x); a0.y = fmaf(A0,w4.y,a0.y); a0.z = fmaf(A0,w4.z,a0.z); a0.w = fmaf(A0,w4.w,a0.w);
      a1.x = fmaf(A1,w4.x,a1.x); a1.y = fmaf(A1,w4.y,a1.y); a1.z = fmaf(A1,w4.z,a1.z); a1.w = fmaf(A1,w4.w,a1.w);
      a2.x = fmaf(A2,w4.x,a2.x); a2.y = fmaf(A2,w4.y,a2.y); a2.z = fmaf(A2,w4.z,a2.z); a2.w = fmaf(A2,w4.w,a2.w);
      a3.x = fmaf(A3,w4.x,a3.x); a3.y = fmaf(A3,w4.y,a3.y); a3.z = fmaf(A3,w4.z,a3.z); a3.w = fmaf(A3,w4.w,a3.w);
    }
    float4 accs[4] = {a0,a1,a2,a3};
    #pragma unroll
    for (int i = 0; i < 4; ++i){
      int m = m0 + ch*32 + ty + 8*i;
      int t = m >> 7, b = m & 127;
      *(float4*)&out[((t*SS + k)*BB + b)*HH + d0] = accs[i];
    }
    __syncthreads();
  }
}

__global__ __launch_bounds__(256) void proj_fo(const float* __restrict__ tilde,
                                               const float* __restrict__ Wf, const float* __restrict__ bf,
                                               const float* __restrict__ Wo, const float* __restrict__ bo,
                                               float* __restrict__ xf, float* __restrict__ xo){
  const int iso = blockIdx.y;
  const float* W = iso ? Wo : Wf;
  const float* bias = iso ? bo : bf;
  float* out = iso ? xo : xf;
  const int m0 = blockIdx.x * 128;
  const int tid = threadIdx.x;
  __shared__ float Wl[HH*HH];
  __shared__ float Al[32*HH];
  for (int u = 0; u < 64; ++u) Wl[u*256 + tid] = W[u*256 + tid];
  const int tx = tid & 31, ty = tid >> 5;
  const int d0 = tx*4;
  float4 bv = *(const float4*)&bias[d0];
  __syncthreads();
  for (int ch = 0; ch < 4; ++ch){
    const float* Arow = tilde + (size_t)(m0 + ch*32)*HH;
    #pragma unroll
    for (int u = 0; u < 4; ++u)
      *(float4*)&Al[u*1024 + tid*4] = *(const float4*)&Arow[u*1024 + tid*4];
    __syncthreads();
    float4 a0 = bv, a1 = bv, a2 = bv, a3 = bv;
    for (int h = 0; h < HH; ++h){
      float4 w4 = *(const float4*)&Wl[h*HH + d0];
      float A0 = Al[(ty   )*HH + h], A1 = Al[(ty+ 8)*HH + h];
      float A2 = Al[(ty+16)*HH + h], A3 = Al[(ty+24)*HH + h];
      a0.x = fmaf(A0,w4.x,a0.x); a0.y = fmaf(A0,w4.y,a0.y); a0.z = fmaf(A0,w4.z,a0.z); a0.w = fmaf(A0,w4.w,a0.w);
      a1.x = fmaf(A1,w4.x,a1.x); a1.y = fmaf(A1,w4.y,a1.y); a1.z = fmaf(A1,w4.z,a1.z); a1.w = fmaf(A1,w4.w,a1.w);
      a2.x = fmaf(A2,w4.x,a2.x); a2.y = fmaf(A2,w4.y,a2.y); a2.z = fmaf(A2,w4.z,a2.z); a2.w = fmaf(A2,w4.w,a2.w);
      a3.x = fmaf(A3,w4.x,a3.x); a3.y = fmaf(A3,w4.y,a3.y); a3.z = fmaf(A3,w4.z,a3.z); a3.w = fmaf(A3,w4.w,a3.w);
    }
    float4 accs[4] = {a0,a1,a2,a3};
    #pragma unroll
    for (int i = 0; i < 4; ++i){
      int m = m0 + ch*32 + ty + 8*i;
      *(float4*)&out[(size_t)m*HH + d0] = accs[i];
    }
    __syncthreads();
  }
}

// ---------------- phase D: DATAFLOW-sync 2D weight-stationary MI-LSTM scan ----------------
// panR is ROW-major [dsl][row*132 + col] (plane stride 2120): GEMM stores 8 b128
// at row*132+c0g (even bank spread); epilogue reads 4 b128 per plane.
__global__ __launch_bounds__(512) void mi_coop(
    const float* __restrict__ ubig,
    const float* __restrict__ xi, const float* __restrict__ xc,
    const float* __restrict__ xf, const float* __restrict__ xo,
    const float* __restrict__ headW, const float* __restrict__ headb,
    float* hR, float* cR,
    float* act, int* flags, float* __restrict__ out)
{
  const int bk = blockIdx.x;
  const int tid = threadIdx.x;
  __shared__ float Wl[16928];                   // 67.7KB weights, persistent
  __shared__ __align__(16) float hLT[2584];     // 10.3KB transposed state
  __shared__ __align__(16) float panR[4*2120];  // 33.9KB partials, row-major
  __shared__ float lL[10*128];
  __shared__ float part[8][8];
  __shared__ float uL[10];

  const int rg = bk / 23, cg = bk - rg*23;
  const int rb0 = rg*16;
  int btype; int xk = 0;
  if (cg < 10){ btype = 0; xk = cg; }
  else if (cg < 20){ btype = 1; xk = cg - 10; }
  else if (cg == 20) btype = 2;
  else if (cg == 21) btype = 3;
  else btype = 4;

  // weights
  for (int idx = tid; idx < 128*128; idx += 512){
    int h = idx >> 7, c = idx & 127;
    Wl[h*132 + ((h>>5)<<3) + (c ^ (((c>>3)&3)<<2))] = ubig[(size_t)h*NCOL + cg*128 + c];
  }

  // GEMM thread map (tid<256)
  const int dsl = tid & 3, ctl2 = (tid >> 2) & 31, rt = (tid >> 7) & 1;
  const int c0g = ctl2*4;
  const int keyc = ((ctl2 >> 1) & 3) << 2;

  // epilogue map (all 512): row erow (0..15), cols ec0..ec0+3
  const int erow = tid >> 5, ec0 = (tid & 31) * 4;
  const float* xrd = nullptr; size_t xrd_step = 0;
  if (btype == 0){ xrd = xi + ((size_t)xk*BB + rb0 + erow)*HH + ec0; xrd_step = (size_t)SS*BB*HH; }
  else if (btype == 1){ xrd = xc + ((size_t)xk*BB + rb0 + erow)*HH + ec0; xrd_step = (size_t)SS*BB*HH; }
  else if (btype == 2){ xrd = xf + (size_t)(rb0 + erow)*HH + ec0; xrd_step = (size_t)BB*HH; }
  else if (btype == 3){ xrd = xo + (size_t)(rb0 + erow)*HH + ec0; xrd_step = (size_t)BB*HH; }

  // P map: 1 row per block (bk<128); wave wv handles stream k = wv (+8 for wv<2)
  const bool isP = (bk < BB);
  const int pb = bk;
  const int rgP = pb >> 4;
  const int wv = tid >> 6, lane = tid & 63;
  float c_reg = 0.f;
  float hw = headW[tid & 127];
  float hb = headb[0];

  int* flag_g = flags;
  int* flag_p = flags + 192;
  const float* arow = act + (size_t)pb*NCOL;   // only dereferenced when isP

  for (int t = 0; t < TT; ++t){
    // ---------- x prefetch (independent of flags) ----------
    float4 xv = make_float4(0.f, 0.f, 0.f, 0.f);
    if (btype != 4) xv = *(const float4*)(xrd + (size_t)t*xrd_step);
    // ---------- WAIT_G: h rows ready ----------
    if (tid < 16){
      while (aldi(&flag_p[rb0 + tid]) < t) __builtin_amdgcn_s_sleep(1);
    }
    __syncthreads();
    asm volatile("" ::: "memory");
    // ---------- stage 16 h-rows transposed ----------
    const float* src = (btype == 4) ? cR : hR;
    {
      int bl = tid >> 5;                 // 0..15 local row
      int d4 = (tid & 31) * 4;
      f32x4v sv = ald4(&src[(size_t)(rb0 + bl)*HH + d4]);
      asm volatile("s_waitcnt vmcnt(0)" ::: "memory");
      int base = d4*20 + ((d4>>5)<<3);
      int slot = bl ^ (((d4 >> 4) & 3) << 2);
      hLT[base + slot]      = sv.x;
      hLT[base + 20 + slot] = sv.y;
      hLT[base + 40 + slot] = sv.z;
      hLT[base + 60 + slot] = sv.w;
    }
    __syncthreads();
    // ---------- G: 8r x 4c x 32d register-tiled GEMM (tid<256, 4 waves) ----------
    if (tid < 256){
      float acc[8][4];
      #pragma unroll
      for (int i = 0; i < 8; ++i)
        #pragma unroll
        for (int j = 0; j < 4; ++j) acc[i][j] = 0.f;
      #pragma unroll 4
      for (int dd = 0; dd < 32; ++dd){
        int d = (dsl << 5) + dd;
        int akey = ((d >> 4) & 3) << 2;
        int hb2 = d*20 + (dsl << 3);
        float4 a0 = *(const float4*)&hLT[hb2 + ((rt*8)     ^ akey)];
        float4 a1 = *(const float4*)&hLT[hb2 + ((rt*8 + 4) ^ akey)];
        float4 w4 = *(const float4*)&Wl[d*132 + (dsl << 3) + (c0g ^ keyc)];
        float a[8] = {a0.x, a0.y, a0.z, a0.w, a1.x, a1.y, a1.z, a1.w};
        float w[4] = {w4.x, w4.y, w4.z, w4.w};
        #pragma unroll
        for (int i = 0; i < 8; ++i)
          #pragma unroll
          for (int j = 0; j < 4; ++j)
            acc[i][j] = fmaf(a[i], w[j], acc[i][j]);
      }
      float* pt = panR + dsl*2120;
      #pragma unroll
      for (int i = 0; i < 8; ++i){
        int row = rt*8 + i;
        *(float4*)&pt[row*132 + c0g] = make_float4(acc[i][0], acc[i][1], acc[i][2], acc[i][3]);
      }
    }
    __syncthreads();
    // ---------- epilogue (512 thr): reduce 4 planes + x + activation + act store ----------
    {
      int base = erow*132 + ec0;
      float4 p0 = *(const float4*)&panR[base];
      float4 p1 = *(const float4*)&panR[2120 + base];
      float4 p2 = *(const float4*)&panR[2*2120 + base];
      float4 p3 = *(const float4*)&panR[3*2120 + base];
      float pv0 = p0.x + p1.x + p2.x + p3.x + xv.x;
      float pv1 = p0.y + p1.y + p2.y + p3.y + xv.y;
      float pv2 = p0.z + p1.z + p2.z + p3.z + xv.z;
      float pv3 = p0.w + p1.w + p2.w + p3.w + xv.w;
      float vout[4];
      float pvs[4] = {pv0, pv1, pv2, pv3};
      #pragma unroll
      for (int u = 0; u < 4; ++u){
        float v;
        if (btype == 1) v = tanhf(pvs[u]);
        else if (btype == 4) v = pvs[u];
        else v = sigf(pvs[u]);
        vout[u] = v;
      }
      float* ap = &act[(size_t)(rb0 + erow)*NCOL + (size_t)cg*128 + ec0];
      ast4(ap, vout[0], vout[1], vout[2], vout[3]);
    }
    asm volatile("s_waitcnt vmcnt(0)" ::: "memory");
    __syncthreads();
    if (tid == 0) asti(&flag_g[bk], t + 1);
    // ---------- WAIT_P: act row pb ready (23 G-blocks of rgP) ----------
    if (isP && tid < 23){
      while (aldi(&flag_g[rgP*23 + tid]) < t + 1) __builtin_amdgcn_s_sleep(1);
    }
    __syncthreads();
    asm volatile("" ::: "memory");
    // ---------- P: attention + cell update (wave-per-stream u-dots) ----------
    if (isP){
      float cw0 = ald(&arow[2816 + lane]);
      float cw1 = ald(&arow[2816 + lane + 64]);
      #pragma unroll
      for (int kk2 = 0; kk2 < 2; ++kk2){
        if (kk2 == 0 || wv < 2){
          int k = wv + kk2*8;
          float li0 = ald(&arow[k*128 + lane])      * ald(&arow[1280 + k*128 + lane]);
          float li1 = ald(&arow[k*128 + lane + 64]) * ald(&arow[1280 + k*128 + lane + 64]);
          lL[k*128 + lane] = li0;
          lL[k*128 + lane + 64] = li1;
          float s = li0*cw0 + li1*cw1;
          s += __shfl_down(s, 32); s += __shfl_down(s, 16); s += __shfl_down(s, 8);
          s += __shfl_down(s, 4);  s += __shfl_down(s, 2);  s += __shfl_down(s, 1);
          if (lane == 0) uL[k] = tanhf(s);
        }
      }
    }
    __syncthreads();
    if (isP && tid < 128){
      float m = uL[0];
      #pragma unroll
      for (int k = 1; k < 10; ++k) m = fmaxf(m, uL[k]);
      float e[10]; float es = 0.f;
      #pragma unroll
      for (int k = 0; k < 10; ++k){ e[k] = expf(uL[k] - m); es += e[k]; }
      float inv = 1.f / es;
      float lm = 0.f;
      #pragma unroll
      for (int k = 0; k < 10; ++k) lm = fmaf(e[k]*inv, lL[k*128 + tid], lm);
      float f = ald(&arow[2560 + tid]);
      float o = ald(&arow[2688 + tid]);
      float cn = fmaf(f, c_reg, lm);
      float hn = o * tanhf(cn);
      c_reg = cn;
      ast(&hR[pb*HH + tid], hn);
      ast(&cR[pb*HH + tid], cn);
      float s = fmaxf(hn, 0.f) * hw;
      s += __shfl_down(s, 32); s += __shfl_down(s, 16); s += __shfl_down(s, 8);
      s += __shfl_down(s, 4);  s += __shfl_down(s, 2);  s += __shfl_down(s, 1);
      if ((tid & 63) == 0) part[wv][6] = s;
    }
    __syncthreads();
    if (isP && tid == 0)
      out[t*BB + pb] = fmaxf(part[0][6] + part[1][6] + hb, 0.f);
    asm volatile("s_waitcnt vmcnt(0)" ::: "memory");
    __syncthreads();
    if (isP && tid == 0) asti(&flag_p[pb], t + 1);
  }
}

extern "C" void kernel_launch(void* const* d_in, const int* in_sizes, int n_in,
                              void* d_out, int out_size, void* d_ws, size_t ws_size,
                              hipStream_t stream) {
  const float* feat  = (const float*)d_in[0];
  const float* Wih   = (const float*)d_in[1];
  const float* Whh   = (const float*)d_in[2];
  const float* bih   = (const float*)d_in[3];
  const float* bhh   = (const float*)d_in[4];
  const float* miWi  = (const float*)d_in[5];
  const float* miUi  = (const float*)d_in[6];
  const float* mibi  = (const float*)d_in[7];
  const float* miWc  = (const float*)d_in[8];
  const float* miUc  = (const float*)d_in[9];
  const float* mibc  = (const float*)d_in[10];
  const float* miWf  = (const float*)d_in[11];
  const float* miUf  = (const float*)d_in[12];
  const float* mibf  = (const float*)d_in[13];
  const float* miWo  = (const float*)d_in[14];
  const float* miUo  = (const float*)d_in[15];
  const float* mibo  = (const float*)d_in[16];
  const float* miWa  = (const float*)d_in[17];
  const float* headW = (const float*)d_in[18];
  const float* headb = (const float*)d_in[19];
  float* out = (float*)d_out;

  float* ws    = (float*)d_ws;
  float* w2t   = ws + OFF_W2T;
  float* bias2 = ws + OFF_BIAS2;
  float* ubig  = ws + OFF_UBIG;
  float* tilde = ws + OFF_TILDE;
  float* xi    = ws + OFF_XI;
  float* xc    = ws + OFF_XC;
  float* xf    = ws + OFF_XF;
  float* xo    = ws + OFF_XO;
  float* hR    = ws + OFF_HT;
  float* cR    = ws + OFF_CT;
  float* act   = ws + OFF_ACT;
  int*   flags = (int*)(ws + OFF_CNT);

  prep_w2t<<<dim3(SZ_W2T/256), dim3(256), 0, stream>>>(Wih, Whh, bih, bhh, w2t, bias2);
  prep_ubig<<<dim3((SZ_UBIG+255)/256), dim3(256), 0, stream>>>(miUi, miUc, miUf, miUo, miWa, ubig);
  init_state<<<dim3(64), dim3(256), 0, stream>>>(flags, hR, cR);
  lstm_scan<<<dim3(160), dim3(1024), 0, stream>>>(feat, w2t, bias2, tilde);
  proj_ic<<<dim3(256, SS, 2), dim3(256), 0, stream>>>(tilde, miWi, mibi, miWc, mibc, xi, xc);
  proj_fo<<<dim3(256, 2), dim3(256), 0, stream>>>(tilde, miWf, mibf, miWo, mibo, xf, xo);

  void* kargs[] = { (void*)&ubig, (void*)&xi, (void*)&xc, (void*)&xf, (void*)&xo,
                    (void*)&headW, (void*)&headb, (void*)&hR, (void*)&cR,
                    (void*)&act, (void*)&flags, (void*)&out };
  hipLaunchCooperativeKernel((const void*)mi_coop, dim3(NBLK), dim3(512), kargs, 0, stream);
}

// Round 17
// 5816.071 us; speedup vs baseline: 1.2568x; 1.2568x over previous
//
#include <hip/hip_runtime.h>
#include <math.h>

// Model: 10 parallel LSTMs -> MI-LSTM w/ stream attention -> linear head.
// All f32 (no fp32-input MFMA on CDNA4; accuracy threshold requires f32).
//
#define SS 10
#define TT 256
#define BB 128
#define HH 128
#define II 128
#define G4 512     // 4H
#define ZK 256     // I + H (fused [x|h] contraction)
#define NCOL 2944  // phase-D fused weight columns: Ui(1280)|Uc(1280)|Uf(128)|Uo(128)|Wa(128)
#define NBLK 184   // cooperative blocks: 8 row-groups x 23 col-groups (16 rows x 128 cols each)

#define SZ_W2T   (SS*ZK*G4)        // 1,310,720
#define SZ_BIAS2 (SS*G4)           // 5,120
#define SZ_UBIG  (HH*NCOL)         // 376,832
#define SZ_TILDE (SS*TT*BB*HH)     // 41,943,040
#define SZ_X     (TT*SS*BB*HH)     // 41,943,040
#define SZ_XFO   (TT*BB*HH)        // 4,194,304

#define OFF_W2T   0
#define OFF_BIAS2 (OFF_W2T + SZ_W2T)
#define OFF_UBIG  (OFF_BIAS2 + SZ_BIAS2)
#define OFF_TILDE (OFF_UBIG + SZ_UBIG)
#define OFF_XI    (OFF_TILDE + SZ_TILDE)
#define OFF_XC    (OFF_XI + SZ_X)
#define OFF_XF    (OFF_XC + SZ_X)
#define OFF_XO    (OFF_XF + SZ_XFO)
#define OFF_HT    (OFF_XO + SZ_XFO)
#define OFF_CT    (OFF_HT + BB*HH)
#define OFF_ACT   (OFF_CT + BB*HH)
#define OFF_CNT   (OFF_ACT + BB*NCOL)

__device__ __forceinline__ float sigf(float x){ return 1.0f/(1.0f+expf(-x)); }

// per-access coherent ops (sc0/sc1 path; no cache-wide wb/inv)
__device__ __forceinline__ float ald(const float* p){
  return __hip_atomic_load(p, __ATOMIC_RELAXED, __HIP_MEMORY_SCOPE_AGENT);
}
__device__ __forceinline__ void ast(float* p, float v){
  __hip_atomic_store(p, v, __ATOMIC_RELAXED, __HIP_MEMORY_SCOPE_AGENT);
}
__device__ __forceinline__ int aldi(const int* p){
  return __hip_atomic_load(p, __ATOMIC_RELAXED, __HIP_MEMORY_SCOPE_AGENT);
}
__device__ __forceinline__ void asti(int* p, int v){
  __hip_atomic_store(p, v, __ATOMIC_RELAXED, __HIP_MEMORY_SCOPE_AGENT);
}
// 16B coherent ops. ext_vector_type binds to a VGPR quad (HIP float4 is a struct, cannot).
typedef float f32x4v __attribute__((ext_vector_type(4)));
__device__ __forceinline__ void ast4(float* p, float a, float b, float c, float d){
  f32x4v w; w.x = a; w.y = b; w.z = c; w.w = d;
  asm volatile("global_store_dwordx4 %0, %1, off sc0 sc1" :: "v"(p), "v"(w) : "memory");
}
__device__ __forceinline__ f32x4v ald4(const float* p){
  f32x4v r;
  asm volatile("global_load_dwordx4 %0, %1, off sc0 sc1" : "=v"(r) : "v"(p) : "memory");
  return r;
}

// ---------------- prep: fused transposed LSTM weights (b128-friendly) ----------------
__global__ __launch_bounds__(256) void prep_w2t(const float* __restrict__ Wih, const float* __restrict__ Whh,
                                                const float* __restrict__ bih, const float* __restrict__ bhh,
                                                float* __restrict__ w2t, float* __restrict__ bias2){
  int idx = blockIdx.x*256 + threadIdx.x;
  if (idx < SZ_W2T){
    int q = idx & 3; int j = (idx >> 2) & 511; int kk4 = (idx >> 11) & 63; int s = idx >> 17;
    int kk = kk4*4 + q;
    float v = (kk < II) ? Wih[(s*G4 + j)*II + kk] : Whh[(s*G4 + j)*HH + (kk - II)];
    w2t[idx] = v;
  }
  if (idx < SZ_BIAS2) bias2[idx] = bih[idx] + bhh[idx];
}

__global__ __launch_bounds__(256) void prep_ubig(const float* __restrict__ Ui, const float* __restrict__ Uc,
                                                 const float* __restrict__ Uf, const float* __restrict__ Uo,
                                                 const float* __restrict__ Wa, float* __restrict__ ubig){
  int idx = blockIdx.x*256 + threadIdx.x;
  if (idx >= SZ_UBIG) return;
  int col = idx % NCOL; int h = idx / NCOL;
  float v;
  if (col < 1280){ int k = col >> 7, d = col & 127; v = Ui[(k*HH + h)*HH + d]; }
  else if (col < 2560){ int c2 = col - 1280; int k = c2 >> 7, d = c2 & 127; v = Uc[(k*HH + h)*HH + d]; }
  else if (col < 2688){ v = Uf[h*HH + (col - 2560)]; }
  else if (col < 2816){ v = Uo[h*HH + (col - 2688)]; }
  else               { v = Wa[h*HH + (col - 2816)]; }
  ubig[idx] = v;
}

// init: flags + h/c state
__global__ __launch_bounds__(256) void init_state(int* flags, float* hR, float* cR){
  int idx = blockIdx.x*256 + threadIdx.x;
  if (idx < 384) flags[idx] = 0;
  if (idx < BB*HH){ hR[idx] = 0.f; cR[idx] = 0.f; }
}

// ---------------- phase B: fused 10x LSTM scan, 4-way split-K, 2 cols/thread (r15) ----------------
// Thread (q = tid>>8, j2 = tid&255) computes cols {j2, j2+256} over contraction
// [q*64, q*64+64) for all 8 rows -> 128 z-broadcasts/wave/step; weights coalesced
// (16B lane stride) and read exactly once per block.
__global__ __launch_bounds__(1024) void lstm_scan(const float* __restrict__ feat, const float* __restrict__ w2t,
                                                  const float* __restrict__ bias2, float* __restrict__ tilde){
  int p = blockIdx.x;                 // 0..159
  int g = (p & 7) * 20 + (p >> 3);
  int s = g >> 4; int rb = g & 15; int b0 = rb * 8;
  const int tid = threadIdx.x;
  const int q = tid >> 8;             // 0..3 K-quarter
  const int j2 = tid & 255;           // col pair base
  __shared__ float z[8][ZK];          // 8KB
  __shared__ float glp[4][8][G4];     // 64KB raw partials
  const float* w2ts = w2t + (size_t)s*ZK*G4;
  const float* wb = w2ts + ((size_t)(q*16)*G4 + j2)*4;
  const int r8 = tid >> 7;            // 0..7 (update row)
  const int k8 = tid & 127;
  float b_i = bias2[s*G4 + k8];
  float b_f = bias2[s*G4 + 128 + k8];
  float b_g = bias2[s*G4 + 256 + k8];
  float b_o = bias2[s*G4 + 384 + k8];
  float c = 0.f;
  z[r8][128 + k8] = 0.f;
  z[r8][k8] = feat[((s*TT + 0)*BB + (b0 + r8))*II + k8];
  __syncthreads();
  for (int t = 0; t < TT; ++t){
    float acc0[8], acc1[8];
    #pragma unroll
    for (int r=0;r<8;++r){ acc0[r] = 0.f; acc1[r] = 0.f; }
    const float* wp = wb;
    const int kb0 = q*64;
    #pragma unroll 4
    for (int it = 0; it < 16; ++it){
      float4 wv0 = *(const float4*)wp;
      float4 wv1 = *(const float4*)(wp + 1024);
      wp += 4*G4;
      #pragma unroll
      for (int r=0;r<8;++r){
        float4 zv = *(const float4*)&z[r][kb0 + it*4];
        acc0[r] = fmaf(zv.w, wv0.w, fmaf(zv.z, wv0.z, fmaf(zv.y, wv0.y, fmaf(zv.x, wv0.x, acc0[r]))));
        acc1[r] = fmaf(zv.w, wv1.w, fmaf(zv.z, wv1.z, fmaf(zv.y, wv1.y, fmaf(zv.x, wv1.x, acc1[r]))));
      }
    }
    #pragma unroll
    for (int r=0;r<8;++r){
      glp[q][r][j2] = acc0[r];
      glp[q][r][j2 + 256] = acc1[r];
    }
    __syncthreads();
    {
      float gi = glp[0][r8][k8]       + glp[1][r8][k8]       + glp[2][r8][k8]       + glp[3][r8][k8]       + b_i;
      float gf = glp[0][r8][128 + k8] + glp[1][r8][128 + k8] + glp[2][r8][128 + k8] + glp[3][r8][128 + k8] + b_f;
      float gg = glp[0][r8][256 + k8] + glp[1][r8][256 + k8] + glp[2][r8][256 + k8] + glp[3][r8][256 + k8] + b_g;
      float go = glp[0][r8][384 + k8] + glp[1][r8][384 + k8] + glp[2][r8][384 + k8] + glp[3][r8][384 + k8] + b_o;
      float i_ = sigf(gi), f_ = sigf(gf), g_ = tanhf(gg), o_ = sigf(go);
      c = f_*c + i_*g_;
      float h = o_*tanhf(c);
      z[r8][128 + k8] = h;
      tilde[((s*TT + t)*BB + (b0 + r8))*HH + k8] = fmaxf(h, 0.f);
      if (t+1 < TT)
        z[r8][k8] = feat[((s*TT + (t+1))*BB + (b0 + r8))*II + k8];
    }
    __syncthreads();
  }
}

// ---------------- phase C: projections (unchanged) ----------------
__global__ __launch_bounds__(256) void proj_ic(const float* __restrict__ tilde,
                                               const float* __restrict__ Wi, const float* __restrict__ bi,
                                               const float* __restrict__ Wc, const float* __restrict__ bc,
                                               float* __restrict__ xi, float* __restrict__ xc){
  const int k = blockIdx.y;
  const int isc = blockIdx.z;
  const float* W = (isc ? Wc : Wi) + k*HH*HH;
  const float* bias = (isc ? bc : bi) + k*HH;
  float* out = isc ? xc : xi;
  const int m0 = blockIdx.x * 128;
  const int tid = threadIdx.x;
  __shared__ float Wl[HH*HH];
  __shared__ float Al[32*HH];
  for (int u = 0; u < 64; ++u) Wl[u*256 + tid] = W[u*256 + tid];
  const int tx = tid & 31, ty = tid >> 5;
  const int d0 = tx*4;
  float4 bv = *(const float4*)&bias[d0];
  __syncthreads();
  for (int ch = 0; ch < 4; ++ch){
    const float* Arow = tilde + (size_t)(k*TT*BB + m0 + ch*32)*HH;
    #pragma unroll
    for (int u = 0; u < 4; ++u)
      *(float4*)&Al[u*1024 + tid*4] = *(const float4*)&Arow[u*1024 + tid*4];
    __syncthreads();
    float4 a0 = bv, a1 = bv, a2 = bv, a3 = bv;
    for (int h = 0; h < HH; ++h){
      float4 w4 = *(const float4*)&Wl[h*HH + d0];
      float A0 = Al[(ty   )*HH + h], A1 = Al[(ty+ 8)*HH + h];
      float A2 = Al[(ty+16)*HH + h], A3 = Al[(ty+24)*HH + h];
      a0.x = fmaf(A0,w4.x,a0.x); a0.y = fmaf(A0,w4.y,a0.y); a0.z = fmaf(A0,w4.z,a0.z); a0.w = fmaf(A0,w4.w,a0.w);
      a1.x = fmaf(A1,w4.x,a1.x); a1.y = fmaf(A1,w4.y,a1.y); a1.z = fmaf(A1,w4.z,a1.z); a1.w = fmaf(A1,w4.w,a1.w);
      a2.x = fmaf(A2,w4.x,a2.x); a2.y = fmaf(A2,w4.y,a2.y); a2.z = fmaf(A2,w4.z,a2.z); a2.w = fmaf(A2,w4.w,a2.w);
      a3.x = fmaf(A3,w4.x,a3.x); a3.y = fmaf(A3,w4.y,a3.y); a3.z = fmaf(A3,w4.z,a3.z); a3.w = fmaf(A3,w4.w,a3.w);
    }
    float4 accs[4] = {a0,a1,a2,a3};
    #pragma unroll
    for (int i = 0; i < 4; ++i){
      int m = m0 + ch*32 + ty + 8*i;
      int t = m >> 7, b = m & 127;
      *(float4*)&out[((t*SS + k)*BB + b)*HH + d0] = accs[i];
    }
    __syncthreads();
  }
}

__global__ __launch_bounds__(256) void proj_fo(const float* __restrict__ tilde,
                                               const float* __restrict__ Wf, const float* __restrict__ bf,
                                               const float* __restrict__ Wo, const float* __restrict__ bo,
                                               float* __restrict__ xf, float* __restrict__ xo){
  const int iso = blockIdx.y;
  const float* W = iso ? Wo : Wf;
  const float* bias = iso ? bo : bf;
  float* out = iso ? xo : xf;
  const int m0 = blockIdx.x * 128;
  const int tid = threadIdx.x;
  __shared__ float Wl[HH*HH];
  __shared__ float Al[32*HH];
  for (int u = 0; u < 64; ++u) Wl[u*256 + tid] = W[u*256 + tid];
  const int tx = tid & 31, ty = tid >> 5;
  const int d0 = tx*4;
  float4 bv = *(const float4*)&bias[d0];
  __syncthreads();
  for (int ch = 0; ch < 4; ++ch){
    const float* Arow = tilde + (size_t)(m0 + ch*32)*HH;
    #pragma unroll
    for (int u = 0; u < 4; ++u)
      *(float4*)&Al[u*1024 + tid*4] = *(const float4*)&Arow[u*1024 + tid*4];
    __syncthreads();
    float4 a0 = bv, a1 = bv, a2 = bv, a3 = bv;
    for (int h = 0; h < HH; ++h){
      float4 w4 = *(const float4*)&Wl[h*HH + d0];
      float A0 = Al[(ty   )*HH + h], A1 = Al[(ty+ 8)*HH + h];
      float A2 = Al[(ty+16)*HH + h], A3 = Al[(ty+24)*HH + h];
      a0.x = fmaf(A0,w4.x,a0.x); a0.y = fmaf(A0,w4.y,a0.y); a0.z = fmaf(A0,w4.z,a0.z); a0.w = fmaf(A0,w4.w,a0.w);
      a1.x = fmaf(A1,w4.x,a1.x); a1.y = fmaf(A1,w4.y,a1.y); a1.z = fmaf(A1,w4.z,a1.z); a1.w = fmaf(A1,w4.w,a1.w);
      a2.x = fmaf(A2,w4.x,a2.x); a2.y = fmaf(A2,w4.y,a2.y); a2.z = fmaf(A2,w4.z,a2.z); a2.w = fmaf(A2,w4.w,a2.w);
      a3.x = fmaf(A3,w4.x,a3.x); a3.y = fmaf(A3,w4.y,a3.y); a3.z = fmaf(A3,w4.z,a3.z); a3.w = fmaf(A3,w4.w,a3.w);
    }
    float4 accs[4] = {a0,a1,a2,a3};
    #pragma unroll
    for (int i = 0; i < 4; ++i){
      int m = m0 + ch*32 + ty + 8*i;
      *(float4*)&out[(size_t)m*HH + d0] = accs[i];
    }
    __syncthreads();
  }
}

// ---------------- phase D: DATAFLOW-sync 2D weight-stationary MI-LSTM scan ----------------
// panR is ROW-major [dsl][row*132 + col] (plane stride 2120): GEMM stores 8 b128
// at row*132+c0g (even bank spread); epilogue reads 4 b128 per plane. (r16, kept)
__global__ __launch_bounds__(512) void mi_coop(
    const float* __restrict__ ubig,
    const float* __restrict__ xi, const float* __restrict__ xc,
    const float* __restrict__ xf, const float* __restrict__ xo,
    const float* __restrict__ headW, const float* __restrict__ headb,
    float* hR, float* cR,
    float* act, int* flags, float* __restrict__ out)
{
  const int bk = blockIdx.x;
  const int tid = threadIdx.x;
  __shared__ float Wl[16928];                   // 67.7KB weights, persistent
  __shared__ __align__(16) float hLT[2584];     // 10.3KB transposed state
  __shared__ __align__(16) float panR[4*2120];  // 33.9KB partials, row-major
  __shared__ float lL[10*128];
  __shared__ float part[8][8];
  __shared__ float uL[10];

  const int rg = bk / 23, cg = bk - rg*23;
  const int rb0 = rg*16;
  int btype; int xk = 0;
  if (cg < 10){ btype = 0; xk = cg; }
  else if (cg < 20){ btype = 1; xk = cg - 10; }
  else if (cg == 20) btype = 2;
  else if (cg == 21) btype = 3;
  else btype = 4;

  // weights
  for (int idx = tid; idx < 128*128; idx += 512){
    int h = idx >> 7, c = idx & 127;
    Wl[h*132 + ((h>>5)<<3) + (c ^ (((c>>3)&3)<<2))] = ubig[(size_t)h*NCOL + cg*128 + c];
  }

  // GEMM thread map (tid<256)
  const int dsl = tid & 3, ctl2 = (tid >> 2) & 31, rt = (tid >> 7) & 1;
  const int c0g = ctl2*4;
  const int keyc = ((ctl2 >> 1) & 3) << 2;

  // epilogue map (all 512): row erow (0..15), cols ec0..ec0+3
  const int erow = tid >> 5, ec0 = (tid & 31) * 4;
  const float* xrd = nullptr; size_t xrd_step = 0;
  if (btype == 0){ xrd = xi + ((size_t)xk*BB + rb0 + erow)*HH + ec0; xrd_step = (size_t)SS*BB*HH; }
  else if (btype == 1){ xrd = xc + ((size_t)xk*BB + rb0 + erow)*HH + ec0; xrd_step = (size_t)SS*BB*HH; }
  else if (btype == 2){ xrd = xf + (size_t)(rb0 + erow)*HH + ec0; xrd_step = (size_t)BB*HH; }
  else if (btype == 3){ xrd = xo + (size_t)(rb0 + erow)*HH + ec0; xrd_step = (size_t)BB*HH; }

  // P map: 1 row per block (bk<128); wave wv handles stream k = wv (+8 for wv<2)
  const bool isP = (bk < BB);
  const int pb = bk;
  const int rgP = pb >> 4;
  const int wv = tid >> 6, lane = tid & 63;
  float c_reg = 0.f;
  float hw = headW[tid & 127];
  float hb = headb[0];

  int* flag_g = flags;
  int* flag_p = flags + 192;
  const float* arow = act + (size_t)pb*NCOL;   // only dereferenced when isP

  for (int t = 0; t < TT; ++t){
    // ---------- x prefetch (independent of flags) ----------
    float4 xv = make_float4(0.f, 0.f, 0.f, 0.f);
    if (btype != 4) xv = *(const float4*)(xrd + (size_t)t*xrd_step);
    // ---------- WAIT_G: h rows ready ----------
    if (tid < 16){
      while (aldi(&flag_p[rb0 + tid]) < t) __builtin_amdgcn_s_sleep(1);
    }
    __syncthreads();
    asm volatile("" ::: "memory");
    // ---------- stage 16 h-rows transposed ----------
    const float* src = (btype == 4) ? cR : hR;
    {
      int bl = tid >> 5;                 // 0..15 local row
      int d4 = (tid & 31) * 4;
      f32x4v sv = ald4(&src[(size_t)(rb0 + bl)*HH + d4]);
      asm volatile("s_waitcnt vmcnt(0)" ::: "memory");
      int base = d4*20 + ((d4>>5)<<3);
      int slot = bl ^ (((d4 >> 4) & 3) << 2);
      hLT[base + slot]      = sv.x;
      hLT[base + 20 + slot] = sv.y;
      hLT[base + 40 + slot] = sv.z;
      hLT[base + 60 + slot] = sv.w;
    }
    __syncthreads();
    // ---------- G: 8r x 4c x 32d register-tiled GEMM (tid<256, 4 waves) ----------
    if (tid < 256){
      float acc[8][4];
      #pragma unroll
      for (int i = 0; i < 8; ++i)
        #pragma unroll
        for (int j = 0; j < 4; ++j) acc[i][j] = 0.f;
      #pragma unroll 4
      for (int dd = 0; dd < 32; ++dd){
        int d = (dsl << 5) + dd;
        int akey = ((d >> 4) & 3) << 2;
        int hb2 = d*20 + (dsl << 3);
        float4 a0 = *(const float4*)&hLT[hb2 + ((rt*8)     ^ akey)];
        float4 a1 = *(const float4*)&hLT[hb2 + ((rt*8 + 4) ^ akey)];
        float4 w4 = *(const float4*)&Wl[d*132 + (dsl << 3) + (c0g ^ keyc)];
        float a[8] = {a0.x, a0.y, a0.z, a0.w, a1.x, a1.y, a1.z, a1.w};
        float w[4] = {w4.x, w4.y, w4.z, w4.w};
        #pragma unroll
        for (int i = 0; i < 8; ++i)
          #pragma unroll
          for (int j = 0; j < 4; ++j)
            acc[i][j] = fmaf(a[i], w[j], acc[i][j]);
      }
      float* pt = panR + dsl*2120;
      #pragma unroll
      for (int i = 0; i < 8; ++i){
        int row = rt*8 + i;
        *(float4*)&pt[row*132 + c0g] = make_float4(acc[i][0], acc[i][1], acc[i][2], acc[i][3]);
      }
    }
    __syncthreads();
    // ---------- epilogue (512 thr): reduce 4 planes + x + activation + act store ----------
    {
      int base = erow*132 + ec0;
      float4 p0 = *(const float4*)&panR[base];
      float4 p1 = *(const float4*)&panR[2120 + base];
      float4 p2 = *(const float4*)&panR[2*2120 + base];
      float4 p3 = *(const float4*)&panR[3*2120 + base];
      float pv0 = p0.x + p1.x + p2.x + p3.x + xv.x;
      float pv1 = p0.y + p1.y + p2.y + p3.y + xv.y;
      float pv2 = p0.z + p1.z + p2.z + p3.z + xv.z;
      float pv3 = p0.w + p1.w + p2.w + p3.w + xv.w;
      float vout[4];
      float pvs[4] = {pv0, pv1, pv2, pv3};
      #pragma unroll
      for (int u = 0; u < 4; ++u){
        float v;
        if (btype == 1) v = tanhf(pvs[u]);
        else if (btype == 4) v = pvs[u];
        else v = sigf(pvs[u]);
        vout[u] = v;
      }
      float* ap = &act[(size_t)(rb0 + erow)*NCOL + (size_t)cg*128 + ec0];
      ast4(ap, vout[0], vout[1], vout[2], vout[3]);
    }
    asm volatile("s_waitcnt vmcnt(0)" ::: "memory");
    __syncthreads();
    if (tid == 0) asti(&flag_g[bk], t + 1);
    // ---------- WAIT_P: act row pb ready (23 G-blocks of rgP) ----------
    if (isP && tid < 23){
      while (aldi(&flag_g[rgP*23 + tid]) < t + 1) __builtin_amdgcn_s_sleep(1);
    }
    __syncthreads();
    asm volatile("" ::: "memory");
    // ---------- P: attention + cell update (wave-per-stream u-dots) ----------
    if (isP){
      float cw0 = ald(&arow[2816 + lane]);
      float cw1 = ald(&arow[2816 + lane + 64]);
      #pragma unroll
      for (int kk2 = 0; kk2 < 2; ++kk2){
        if (kk2 == 0 || wv < 2){
          int k = wv + kk2*8;
          float li0 = ald(&arow[k*128 + lane])      * ald(&arow[1280 + k*128 + lane]);
          float li1 = ald(&arow[k*128 + lane + 64]) * ald(&arow[1280 + k*128 + lane + 64]);
          lL[k*128 + lane] = li0;
          lL[k*128 + lane + 64] = li1;
          float s = li0*cw0 + li1*cw1;
          s += __shfl_down(s, 32); s += __shfl_down(s, 16); s += __shfl_down(s, 8);
          s += __shfl_down(s, 4);  s += __shfl_down(s, 2);  s += __shfl_down(s, 1);
          if (lane == 0) uL[k] = tanhf(s);
        }
      }
    }
    __syncthreads();
    if (isP && tid < 128){
      float m = uL[0];
      #pragma unroll
      for (int k = 1; k < 10; ++k) m = fmaxf(m, uL[k]);
      float e[10]; float es = 0.f;
      #pragma unroll
      for (int k = 0; k < 10; ++k){ e[k] = expf(uL[k] - m); es += e[k]; }
      float inv = 1.f / es;
      float lm = 0.f;
      #pragma unroll
      for (int k = 0; k < 10; ++k) lm = fmaf(e[k]*inv, lL[k*128 + tid], lm);
      float f = ald(&arow[2560 + tid]);
      float o = ald(&arow[2688 + tid]);
      float cn = fmaf(f, c_reg, lm);
      float hn = o * tanhf(cn);
      c_reg = cn;
      ast(&hR[pb*HH + tid], hn);
      ast(&cR[pb*HH + tid], cn);
      float s = fmaxf(hn, 0.f) * hw;
      s += __shfl_down(s, 32); s += __shfl_down(s, 16); s += __shfl_down(s, 8);
      s += __shfl_down(s, 4);  s += __shfl_down(s, 2);  s += __shfl_down(s, 1);
      if ((tid & 63) == 0) part[wv][6] = s;
    }
    __syncthreads();
    if (isP && tid == 0)
      out[t*BB + pb] = fmaxf(part[0][6] + part[1][6] + hb, 0.f);
    asm volatile("s_waitcnt vmcnt(0)" ::: "memory");
    __syncthreads();
    if (isP && tid == 0) asti(&flag_p[pb], t + 1);
  }
}

extern "C" void kernel_launch(void* const* d_in, const int* in_sizes, int n_in,
                              void* d_out, int out_size, void* d_ws, size_t ws_size,
                              hipStream_t stream) {
  const float* feat  = (const float*)d_in[0];
  const float* Wih   = (const float*)d_in[1];
  const float* Whh   = (const float*)d_in[2];
  const float* bih   = (const float*)d_in[3];
  const float* bhh   = (const float*)d_in[4];
  const float* miWi  = (const float*)d_in[5];
  const float* miUi  = (const float*)d_in[6];
  const float* mibi  = (const float*)d_in[7];
  const float* miWc  = (const float*)d_in[8];
  const float* miUc  = (const float*)d_in[9];
  const float* mibc  = (const float*)d_in[10];
  const float* miWf  = (const float*)d_in[11];
  const float* miUf  = (const float*)d_in[12];
  const float* mibf  = (const float*)d_in[13];
  const float* miWo  = (const float*)d_in[14];
  const float* miUo  = (const float*)d_in[15];
  const float* mibo  = (const float*)d_in[16];
  const float* miWa  = (const float*)d_in[17];
  const float* headW = (const float*)d_in[18];
  const float* headb = (const float*)d_in[19];
  float* out = (float*)d_out;

  float* ws    = (float*)d_ws;
  float* w2t   = ws + OFF_W2T;
  float* bias2 = ws + OFF_BIAS2;
  float* ubig  = ws + OFF_UBIG;
  float* tilde = ws + OFF_TILDE;
  float* xi    = ws + OFF_XI;
  float* xc    = ws + OFF_XC;
  float* xf    = ws + OFF_XF;
  float* xo    = ws + OFF_XO;
  float* hR    = ws + OFF_HT;
  float* cR    = ws + OFF_CT;
  float* act   = ws + OFF_ACT;
  int*   flags = (int*)(ws + OFF_CNT);

  prep_w2t<<<dim3(SZ_W2T/256), dim3(256), 0, stream>>>(Wih, Whh, bih, bhh, w2t, bias2);
  prep_ubig<<<dim3((SZ_UBIG+255)/256), dim3(256), 0, stream>>>(miUi, miUc, miUf, miUo, miWa, ubig);
  init_state<<<dim3(64), dim3(256), 0, stream>>>(flags, hR, cR);
  lstm_scan<<<dim3(160), dim3(1024), 0, stream>>>(feat, w2t, bias2, tilde);
  proj_ic<<<dim3(256, SS, 2), dim3(256), 0, stream>>>(tilde, miWi, mibi, miWc, mibc, xi, xc);
  proj_fo<<<dim3(256, 2), dim3(256), 0, stream>>>(tilde, miWf, mibf, miWo, mibo, xf, xo);

  void* kargs[] = { (void*)&ubig, (void*)&xi, (void*)&xc, (void*)&xf, (void*)&xo,
                    (void*)&headW, (void*)&headb, (void*)&hR, (void*)&cR,
                    (void*)&act, (void*)&flags, (void*)&out };
  hipLaunchCooperativeKernel((const void*)mi_coop, dim3(NBLK), dim3(512), kargs, 0, stream);
}